// Round 8
// baseline (81.817 us; speedup 1.0000x reference)
//
#include <hip/hip_runtime.h>

// TripletLoss, N=384, D=512, fp32 in, int labels, fp32 scalar out.
// loss = sum_a sum_p sum_n relu(d(a,p)-d(a,n)+1) / num_valid (diag counts as pos)
//
// R14 post-mortem: 79.6us = 40 (fixed 268MB ws re-poison fill) + K1 + K2 +
// ~10 (2 boundaries). pair_reduce is ~3-5us, so dist_tile ~20-25us: with 144
// blocks < 256 CUs, kernel duration == single-block critical path (8 serial
// stage->barrier->compute rounds, 4 waves/CU, nothing to hide latency with).
//
// R15: K-split dist_tile. Each block computes a PARTIAL d^2 over a 128-wide
// K-chunk (2 of 8 K-tiles): grid 12x12x4 = 576 blocks (2.25/CU), per-block
// path cut 4x. Partials written to 4 D-planes (no sqrt); pair_reduce sums
// the planes + sqrt (3 extra coalesced loads/thread). Diagonal stays exactly
// 0: each partial is a diff^2 of identically-loaded data -> 0. Everything
// else is the R14-verified code verbatim (absmax 0.0).

#define NPTS 384
#define DIM  512
#define TS   32          // C-tile 32x32
#define BK   64
#define PITCH 68         // BK+4 pad floats; 272B row pitch keeps float4 align
#define NT1  256
#define NT2  384
#define NW2  (NT2 / 64)  // 6 waves
#define KSPLIT 4
#define KTPB ((DIM / BK) / KSPLIT)   // 2 K-tiles per block

// ------- K1: partial distance matrix (GEMM-shaped, diff^2, K-split) ---------
__global__ __launch_bounds__(NT1) void dist_tile(const float* __restrict__ X,
                                                 float* __restrict__ Dp) {
    __shared__ float As[TS * PITCH];
    __shared__ float Bs[TS * PITCH];
    const int t  = threadIdx.x;
    const int tx = t & 15, ty = t >> 4;        // 16x16 thread grid, 2x2 per thread
    const int bi = blockIdx.y * TS;
    const int bj = blockIdx.x * TS;
    const int kt0 = blockIdx.z * KTPB;         // this block's K-chunk

    const float4* X4 = (const float4*)X;       // row pitch DIM/4 = 128 float4
    const int r0 = t >> 4, c4 = t & 15;        // staging: 32 rows x 16 float4

    float4 pa0, pa1, pb0, pb1;                 // register prefetch
    int k4 = kt0 * (BK / 4);
    {   // stage first K-tile of this chunk
        pa0 = X4[(size_t)(bi + r0)      * (DIM/4) + k4 + c4];
        pa1 = X4[(size_t)(bi + r0 + 16) * (DIM/4) + k4 + c4];
        pb0 = X4[(size_t)(bj + r0)      * (DIM/4) + k4 + c4];
        pb1 = X4[(size_t)(bj + r0 + 16) * (DIM/4) + k4 + c4];
        *(float4*)&As[ r0       * PITCH + c4*4] = pa0;
        *(float4*)&As[(r0 + 16) * PITCH + c4*4] = pa1;
        *(float4*)&Bs[ r0       * PITCH + c4*4] = pb0;
        *(float4*)&Bs[(r0 + 16) * PITCH + c4*4] = pb1;
    }
    __syncthreads();

    float acc00 = 0.f, acc01 = 0.f, acc10 = 0.f, acc11 = 0.f;

    for (int kt = kt0; kt < kt0 + KTPB; ++kt) {
        if (kt < kt0 + KTPB - 1) {             // prefetch next K-tile into regs
            k4 = (kt + 1) * (BK / 4);
            pa0 = X4[(size_t)(bi + r0)      * (DIM/4) + k4 + c4];
            pa1 = X4[(size_t)(bi + r0 + 16) * (DIM/4) + k4 + c4];
            pb0 = X4[(size_t)(bj + r0)      * (DIM/4) + k4 + c4];
            pb1 = X4[(size_t)(bj + r0 + 16) * (DIM/4) + k4 + c4];
        }
#pragma unroll
        for (int kk = 0; kk < BK / 4; ++kk) {
            const float4 a0 = *(const float4*)&As[(2*ty)   * PITCH + kk*4];
            const float4 a1 = *(const float4*)&As[(2*ty+1) * PITCH + kk*4];
            const float4 b0 = *(const float4*)&Bs[(2*tx)   * PITCH + kk*4];
            const float4 b1 = *(const float4*)&Bs[(2*tx+1) * PITCH + kk*4];
            float d;
            d = a0.x - b0.x; acc00 = fmaf(d, d, acc00);
            d = a0.y - b0.y; acc00 = fmaf(d, d, acc00);
            d = a0.z - b0.z; acc00 = fmaf(d, d, acc00);
            d = a0.w - b0.w; acc00 = fmaf(d, d, acc00);
            d = a0.x - b1.x; acc01 = fmaf(d, d, acc01);
            d = a0.y - b1.y; acc01 = fmaf(d, d, acc01);
            d = a0.z - b1.z; acc01 = fmaf(d, d, acc01);
            d = a0.w - b1.w; acc01 = fmaf(d, d, acc01);
            d = a1.x - b0.x; acc10 = fmaf(d, d, acc10);
            d = a1.y - b0.y; acc10 = fmaf(d, d, acc10);
            d = a1.z - b0.z; acc10 = fmaf(d, d, acc10);
            d = a1.w - b0.w; acc10 = fmaf(d, d, acc10);
            d = a1.x - b1.x; acc11 = fmaf(d, d, acc11);
            d = a1.y - b1.y; acc11 = fmaf(d, d, acc11);
            d = a1.z - b1.z; acc11 = fmaf(d, d, acc11);
            d = a1.w - b1.w; acc11 = fmaf(d, d, acc11);
        }
        __syncthreads();
        if (kt < kt0 + KTPB - 1) {
            *(float4*)&As[ r0       * PITCH + c4*4] = pa0;
            *(float4*)&As[(r0 + 16) * PITCH + c4*4] = pa1;
            *(float4*)&Bs[ r0       * PITCH + c4*4] = pb0;
            *(float4*)&Bs[(r0 + 16) * PITCH + c4*4] = pb1;
            __syncthreads();
        }
    }

    // partial d^2 (no sqrt); diagonal tiles: identical As/Bs rows -> exact 0
    float* Dps = Dp + (size_t)blockIdx.z * NPTS * NPTS;
    const int gi = bi + 2*ty, gj = bj + 2*tx;
    *(float2*)&Dps[(size_t)gi      * NPTS + gj] = make_float2(acc00, acc01);
    *(float2*)&Dps[(size_t)(gi+1)  * NPTS + gj] = make_float2(acc10, acc11);
}

// ---------------- K2: plane-sum + compaction + pair sum + finish ------------
__global__ __launch_bounds__(NT2) void pair_reduce(const float* __restrict__ Dp,
                                                   const int* __restrict__ labels,
                                                   float* __restrict__ out) {
    __shared__ float s_dp[NPTS];
    __shared__ float s_dn[NPTS];
    __shared__ int   s_lab[NPTS] __attribute__((aligned(16)));
    __shared__ int   s_cp[NW2], s_cn[NW2];
    __shared__ float s_red[NW2];
    __shared__ int   s_nv[NW2];

    const int t = threadIdx.x, lane = t & 63, w = t >> 6;
    const int a = blockIdx.x;

    // 4 independent plane loads issue back-to-back (MLP), then sum + sqrt
    const size_t idx = (size_t)a * NPTS + t;
    const float p0 = Dp[idx];
    const float p1 = Dp[idx + (size_t)NPTS * NPTS];
    const float p2 = Dp[idx + (size_t)2 * NPTS * NPTS];
    const float p3 = Dp[idx + (size_t)3 * NPTS * NPTS];
    s_lab[t] = labels[t];
    const int lab_a = labels[a];
    const float dv = sqrtf((p0 + p1) + (p2 + p3));   // diag: all partials 0 -> 0
    __syncthreads();

    // ---- ballot compaction into positives / negatives (proven) -------------
    const bool isp = (s_lab[t] == lab_a);         // diag j==a counts as pos
    const unsigned long long m = __ballot(isp);
    if (lane == 0) { s_cp[w] = __popcll(m); s_cn[w] = 64 - __popcll(m); }
    __syncthreads();

    int basep = 0, basen = 0, np = 0, nn = 0;
#pragma unroll
    for (int i = 0; i < NW2; ++i) {
        if (i < w) { basep += s_cp[i]; basen += s_cn[i]; }
        np += s_cp[i]; nn += s_cn[i];
    }
    const unsigned long long blw = (1ull << lane) - 1ull;   // lane<64, safe
    if (isp) s_dp[basep + __popcll(m  & blw)] = dv;
    else     s_dn[basen + __popcll(~m & blw)] = dv;
    __syncthreads();

    // ---- pair sum: thread t owns negative n = t ----------------------------
    const bool  va  = (t < nn);
    const float dna = va ? s_dn[t] : 0.f;
    float local = 0.f;
    for (int p = 0; p < np; ++p) {
        const float c = s_dp[p] + 1.0f;           // MARGIN
        if (va) local += fmaxf(c - dna, 0.f);
    }

    // ---- global num_valid from labels alone (identical in every block) -----
    // num_valid = sum_t np(t) * (384 - np(t)); np(t) = #{j: lab[j]==lab[t]}
    const int myl = s_lab[t];
    int npt = 0;
    const int4* L4 = (const int4*)s_lab;
#pragma unroll 8
    for (int j4 = 0; j4 < NPTS / 4; ++j4) {
        const int4 l = L4[j4];                    // broadcast read
        npt += (l.x == myl) + (l.y == myl) + (l.z == myl) + (l.w == myl);
    }
    int nvl = npt * (NPTS - npt);

    // ---- block reduce + atomic finish --------------------------------------
    for (int off = 32; off; off >>= 1) {
        local += __shfl_down(local, off, 64);
        nvl   += __shfl_down(nvl,   off, 64);
    }
    if (lane == 0) { s_red[w] = local; s_nv[w] = nvl; }
    __syncthreads();
    if (t == 0) {
        float bs = 0.f; int nv = 0;
#pragma unroll
        for (int i = 0; i < NW2; ++i) { bs += s_red[i]; nv += s_nv[i]; }
        // out is memset to 0 by the harness before each verified launch
        atomicAdd(out, (float)((double)bs / ((double)nv + 1e-16)));
    }
}

extern "C" void kernel_launch(void* const* d_in, const int* in_sizes, int n_in,
                              void* d_out, int out_size, void* d_ws, size_t ws_size,
                              hipStream_t stream) {
    (void)in_sizes; (void)n_in; (void)out_size; (void)ws_size;
    const float* X      = (const float*)d_in[0];
    const int*   labels = (const int*)d_in[1];

    float* Dp = (float*)d_ws;    // 4 planes x 589824 B = 2.36 MB, rewritten each run

    dist_tile  <<<dim3(NPTS / TS, NPTS / TS, KSPLIT), dim3(NT1), 0, stream>>>(X, Dp);
    pair_reduce<<<dim3(NPTS),                         dim3(NT2), 0, stream>>>(Dp, labels,
                                                                              (float*)d_out);
}

// Round 9
// 70.801 us; speedup vs baseline: 1.1556x; 1.1556x over previous
//
#include <hip/hip_runtime.h>

// TripletLoss, N=384, D=512, fp32 in, int labels, fp32 scalar out.
// loss = sum_a sum_p sum_n relu(d(a,p)-d(a,n)+1) / num_valid (diag counts as pos)
//
// R15 post-mortem: K-split regressed (81.8 vs 79.6) -> the scalar-FMA tile
// engine is the floor: 2.1 MB of LDS reads per block (64B LDS per 16 FLOP)
// ~= 7us serialization/block no matter how K is split. R16 swaps the engine
// for MFMA: d^2 = |a|^2+|b|^2-2ab with the cross term as a bf16 Gram tile
// (mfma_f32_16x16x32_bf16). Per block: stage 32+32 rows as bf16 in LDS
// (XOR-swizzled, byte ^= (row&7)<<4 -> 2-way = free), 4 waves x 16 k-chunks
// x {2 ds_read_b128 + 1 MFMA} -> 16x less LDS traffic. Norms computed from
// the SAME bf16 LDS values (d^2 = |a~-b~|^2 >= 0 in exact math; clamp +
// forced diag 0). bf16 ~ 0.4% input perturbation -> loss error ~1e-4, well
// under the 2.17e-2 threshold. K2 = R14's proven pair_reduce verbatim.

#define NPTS 384
#define DIM  512
#define NT2  384
#define NW2  (NT2 / 64)  // 6 waves

typedef __attribute__((ext_vector_type(8))) short bf16x8;
typedef __attribute__((ext_vector_type(4))) float f32x4;

__device__ __forceinline__ ushort f2bf(float f) {     // RNE f32 -> bf16
    uint u = __float_as_uint(f);
    u += 0x7fffu + ((u >> 16) & 1u);
    return (ushort)(u >> 16);
}

// ---------------- K1: distance tiles via bf16 MFMA Gram ---------------------
__global__ __launch_bounds__(256) void dist_mfma(const float* __restrict__ X,
                                                 float* __restrict__ D) {
    __shared__ ushort s_A[32 * 512] __attribute__((aligned(16)));  // 32 KB
    __shared__ ushort s_B[32 * 512] __attribute__((aligned(16)));  // 32 KB
    __shared__ float  s_nrmp[4][64];                               // 1 KB

    const int t    = threadIdx.x;
    const int lane = t & 63, w = t >> 6;
    const int wr   = w >> 1,  wc = w & 1;        // 2x2 wave grid of 16x16 C-tiles
    const int bi   = blockIdx.y * 32;
    const int bj   = blockIdx.x * 32;

    const float4* X4 = (const float4*)X;         // row pitch DIM/4 = 128

    // ---- stage A/B tiles as bf16, swizzled; 32 coalesced float4/thread -----
#pragma unroll 8
    for (int p = 0; p < 32; ++p) {
        const int idx  = p * 256 + t;            // 0..8191
        const int side = idx >> 12;              // 0=A, 1=B (uniform per p)
        const int row  = (idx >> 7) & 31;
        const int col4 = idx & 127;
        const int grow = (side ? bj : bi) + row;
        const float4 v = X4[(size_t)grow * 128 + col4];
        const uint lo = (uint)f2bf(v.x) | ((uint)f2bf(v.y) << 16);
        const uint hi = (uint)f2bf(v.z) | ((uint)f2bf(v.w) << 16);
        const int off = (col4 * 8) ^ ((row & 7) << 4);   // XOR swizzle, 16B grain
        char* dst = (side ? (char*)s_B : (char*)s_A) + row * 1024 + off;
        *(uint2*)dst = make_uint2(lo, hi);
    }
    __syncthreads();

    // ---- norms from the staged bf16 values: lane=row, wave=k-quarter -------
    {
        const int row  = lane;                   // 0..31 A rows, 32..63 B rows
        const int side = row >> 5, r = row & 31;
        const char* src = (side ? (const char*)s_B : (const char*)s_A) + r * 1024;
        float nrm = 0.f;
#pragma unroll
        for (int c = 0; c < 16; ++c) {
            const int cb = (w * 16 + c) * 16;    // 16B chunk within the 1KB row
            const bf16x8 hv = *(const bf16x8*)(src + (cb ^ ((r & 7) << 4)));
#pragma unroll
            for (int j = 0; j < 8; ++j) {
                const float f = __uint_as_float(((uint)(ushort)hv[j]) << 16);
                nrm = fmaf(f, f, nrm);
            }
        }
        s_nrmp[w][row] = nrm;
    }

    // ---- Gram tile: 16 k-chunks x mfma_f32_16x16x32_bf16 -------------------
    f32x4 acc = {0.f, 0.f, 0.f, 0.f};
    const int ar = wr * 16 + (lane & 15);        // A local row fed by this lane
    const int br = wc * 16 + (lane & 15);        // B local row (= C col)
    const char* pa = (const char*)s_A + ar * 1024;
    const char* pb = (const char*)s_B + br * 1024;
    const int kg = (lane >> 4) * 16;             // lane's k-group byte offset
#pragma unroll
    for (int kt = 0; kt < 16; ++kt) {
        const int kb = kt * 64 + kg;
        const bf16x8 af = *(const bf16x8*)(pa + (kb ^ ((ar & 7) << 4)));
        const bf16x8 bf = *(const bf16x8*)(pb + (kb ^ ((br & 7) << 4)));
        acc = __builtin_amdgcn_mfma_f32_16x16x32_bf16(af, bf, acc, 0, 0, 0);
    }
    __syncthreads();                              // s_nrmp complete

    // ---- epilogue: d = sqrt(max(nA + nB - 2*G, 0)); diag forced 0 ----------
    const float nB = s_nrmp[0][32 + br] + s_nrmp[1][32 + br] +
                     s_nrmp[2][32 + br] + s_nrmp[3][32 + br];
#pragma unroll
    for (int v = 0; v < 4; ++v) {
        const int il = wr * 16 + (lane >> 4) * 4 + v;    // C row -> A local row
        const float nA = s_nrmp[0][il] + s_nrmp[1][il] +
                         s_nrmp[2][il] + s_nrmp[3][il];
        const float d2 = nA + nB - 2.f * acc[v];
        const int gi = bi + il, gj = bj + br;
        D[(size_t)gi * NPTS + gj] = (gi == gj) ? 0.f : sqrtf(fmaxf(d2, 0.f));
    }
}

// ---------------- K2: compaction + pair sum + global finish (R14 verbatim) --
__global__ __launch_bounds__(NT2) void pair_reduce(const float* __restrict__ D,
                                                   const int* __restrict__ labels,
                                                   float* __restrict__ out) {
    __shared__ float s_dp[NPTS];
    __shared__ float s_dn[NPTS];
    __shared__ int   s_lab[NPTS] __attribute__((aligned(16)));
    __shared__ int   s_cp[NW2], s_cn[NW2];
    __shared__ float s_red[NW2];
    __shared__ int   s_nv[NW2];

    const int t = threadIdx.x, lane = t & 63, w = t >> 6;
    const int a = blockIdx.x;

    const float dv = D[(size_t)a * NPTS + t];
    s_lab[t] = labels[t];
    const int lab_a = labels[a];
    __syncthreads();

    const bool isp = (s_lab[t] == lab_a);         // diag j==a counts as pos
    const unsigned long long m = __ballot(isp);
    if (lane == 0) { s_cp[w] = __popcll(m); s_cn[w] = 64 - __popcll(m); }
    __syncthreads();

    int basep = 0, basen = 0, np = 0, nn = 0;
#pragma unroll
    for (int i = 0; i < NW2; ++i) {
        if (i < w) { basep += s_cp[i]; basen += s_cn[i]; }
        np += s_cp[i]; nn += s_cn[i];
    }
    const unsigned long long blw = (1ull << lane) - 1ull;   // lane<64, safe
    if (isp) s_dp[basep + __popcll(m  & blw)] = dv;
    else     s_dn[basen + __popcll(~m & blw)] = dv;
    __syncthreads();

    const bool  va  = (t < nn);
    const float dna = va ? s_dn[t] : 0.f;
    float local = 0.f;
    for (int p = 0; p < np; ++p) {
        const float c = s_dp[p] + 1.0f;           // MARGIN
        if (va) local += fmaxf(c - dna, 0.f);
    }

    // global num_valid from labels alone (identical in every block)
    const int myl = s_lab[t];
    int npt = 0;
    const int4* L4 = (const int4*)s_lab;
#pragma unroll 8
    for (int j4 = 0; j4 < NPTS / 4; ++j4) {
        const int4 l = L4[j4];
        npt += (l.x == myl) + (l.y == myl) + (l.z == myl) + (l.w == myl);
    }
    int nvl = npt * (NPTS - npt);

    for (int off = 32; off; off >>= 1) {
        local += __shfl_down(local, off, 64);
        nvl   += __shfl_down(nvl,   off, 64);
    }
    if (lane == 0) { s_red[w] = local; s_nv[w] = nvl; }
    __syncthreads();
    if (t == 0) {
        float bs = 0.f; int nv = 0;
#pragma unroll
        for (int i = 0; i < NW2; ++i) { bs += s_red[i]; nv += s_nv[i]; }
        // out is memset to 0 by the harness before each verified launch
        atomicAdd(out, (float)((double)bs / ((double)nv + 1e-16)));
    }
}

extern "C" void kernel_launch(void* const* d_in, const int* in_sizes, int n_in,
                              void* d_out, int out_size, void* d_ws, size_t ws_size,
                              hipStream_t stream) {
    (void)in_sizes; (void)n_in; (void)out_size; (void)ws_size;
    const float* X      = (const float*)d_in[0];
    const int*   labels = (const int*)d_in[1];

    float* Dmat = (float*)d_ws;                   // 589824 B, rewritten each run

    dist_mfma  <<<dim3(NPTS / 32, NPTS / 32), dim3(256), 0, stream>>>(X, Dmat);
    pair_reduce<<<dim3(NPTS),                 dim3(NT2), 0, stream>>>(Dmat, labels,
                                                                     (float*)d_out);
}